// Round 5
// baseline (147.136 us; speedup 1.0000x reference)
//
#include <hip/hip_runtime.h>
#include <math.h>

#define BB 16
#define NN 4096            // N == M == 4096
#define KK 128
#define RT 2048            // rows per block  (8 per thread)
#define CT 128             // cols per block  (2 packed groups of 64)
#define RPT 8              // rows per thread
#define TPB 256
#define NRTILE (NN / RT)   // 2
#define NCTILE (NN / CT)   // 32
#define W_POINT  1.0f
#define W_COEFF  0.5f
#define W_AFFINE 0.5f

typedef float f2 __attribute__((ext_vector_type(2)));

__device__ inline float min3f(float a, float b, float c) {
    float r;
    asm("v_min3_f32 %0, %1, %2, %3" : "=v"(r) : "v"(a), "v"(b), "v"(c));
    return r;
}
__device__ inline f2 pk_add(f2 a, f2 b) {
    f2 r;
    asm("v_pk_add_f32 %0, %1, %2" : "=v"(r) : "v"(a), "v"(b));
    return r;
}
__device__ inline f2 pk_fma(f2 a, f2 b, f2 c) {
    f2 r;
    asm("v_pk_fma_f32 %0, %1, %2, %3" : "=v"(r) : "v"(a), "v"(b), "v"(c));
    return r;
}

__device__ inline void compute_affine(const float* __restrict__ aff,
                                      float R[9], float sc[3], float tr[3]) {
    float ax = aff[0], ay = aff[1], az = aff[2];
    tr[0] = aff[3]; tr[1] = aff[4]; tr[2] = aff[5];
    sc[0] = aff[6]; sc[1] = aff[7]; sc[2] = aff[8];
    float cx = cosf(ax), sx = sinf(ax);
    float cy = cosf(ay), sy = sinf(ay);
    float cz = cosf(az), sz = sinf(az);
    R[0] = cy * cz;                 R[1] = -cy * sz;                R[2] = sy;
    R[3] = cx * sz + sx * sy * cz;  R[4] = cx * cz - sx * sy * sz;  R[5] = -sx * cy;
    R[6] = sx * sz - cx * sy * cz;  R[7] = sx * cz + cx * sy * sz;  R[8] = cx * cy;
}

__device__ inline void apply_affine(const float R[9], const float sc[3], const float tr[3],
                                    float x, float y, float z,
                                    float& ox, float& oy, float& oz) {
    ox = fmaf(fmaf(x, R[0], fmaf(y, R[3], z * R[6])), sc[0], tr[0]);
    oy = fmaf(fmaf(x, R[1], fmaf(y, R[4], z * R[7])), sc[1], tr[1]);
    oz = fmaf(fmaf(x, R[2], fmaf(y, R[5], z * R[8])), sc[2], tr[2]);
}

// One-pass Chamfer, packed-fp32 inner loop. Block owns a 2048x128 tile of the
// d2 matrix (pair evaluated ONCE). Cols live in LDS as SoA float2 arrays
// pairing col s with col s+64, so the two column-groups share one
// v_pk_add/v_pk_fma stream. Row-mins stay thread-local; col-mins rotate one
// lane per iter (ds_bpermute) so no cross-lane tree is needed. Partial
// results are OWNED (plain stores, no atomics, no ws init):
//   rp[(b*32+ctile)*NN + row]            row-partial mins (min over 32 later)
//   cp[((b*2+rtile)*4+wid)*NN + col]     per-wave col-partial mins (min over 8)
__global__ __launch_bounds__(TPB, 4) void chamfer_kernel(
        const float* __restrict__ pred_shape,
        const float* __restrict__ targ_shape,
        const float* __restrict__ targ_affine,
        float* __restrict__ rp,
        float* __restrict__ cp) {
    __shared__ float ldsb[4 * CT];   // x[128] | y[128] | z[128] | w[128], pair-interleaved

    const int bx    = blockIdx.x;
    const int ctile = bx & (NCTILE - 1);
    const int rtile = (bx >> 5) & (NRTILE - 1);
    const int b     = bx >> 6;
    const int tid   = threadIdx.x;
    const int lane  = tid & 63;
    const int wid   = tid >> 6;

    // ---- stage 128 transformed target cols (pair slot s <- cols s, s+64) ----
    if (tid < CT) {
        float R[9], sc[3], tr[3];
        compute_affine(targ_affine + b * 9, R, sc, tr);
        const int s = tid & 63, h = tid >> 6;
        const float* t = targ_shape + ((size_t)b * NN + ctile * CT + tid) * 3;
        float mx, my, mz;
        apply_affine(R, sc, tr, t[0], t[1], t[2], mx, my, mz);
        ldsb[0 * CT + 2 * s + h] = mx;
        ldsb[1 * CT + 2 * s + h] = my;
        ldsb[2 * CT + 2 * s + h] = mz;
        ldsb[3 * CT + 2 * s + h] = fmaf(mx, mx, fmaf(my, my, mz * mz));
    }

    // ---- load 8 pred rows per thread; broadcast constants as pairs ----
    const int rowbase = rtile * RT;
    f2 axp[RPT], ayp[RPT], azp[RPT], q2p[RPT];
    float rmin[RPT];
    #pragma unroll
    for (int k = 0; k < RPT; ++k) {
        const float* p = pred_shape + ((size_t)b * NN + rowbase + k * TPB + tid) * 3;
        float x = p[0], y = p[1], z = p[2];
        float q2 = fmaf(x, x, fmaf(y, y, z * z));
        axp[k] = (f2){-2.0f * x, -2.0f * x};
        ayp[k] = (f2){-2.0f * y, -2.0f * y};
        azp[k] = (f2){-2.0f * z, -2.0f * z};
        q2p[k] = (f2){q2, q2};
        rmin[k] = 1e30f;
    }
    __syncthreads();

    // ---- rotating scan: iter i, lane l handles pair slot (l+i)&63 ----
    const f2* base = (const f2*)ldsb;        // [0,64)=x [64,128)=y [128,192)=z [192,256)=w
    f2 cr = (f2){1e30f, 1e30f};              // rotating col-min accumulators (lo,hi group)
    const int rot = ((lane + 1) & 63) << 2;
    int idx = lane;
    for (int i = 0; i < 64; ++i) {
        f2 x01 = base[idx];
        f2 y01 = base[64 + idx];
        f2 z01 = base[128 + idx];
        f2 w01 = base[192 + idx];
        float cA, cB;
        #pragma unroll
        for (int k = 0; k < RPT; k += 2) {
            f2 s0 = pk_add(q2p[k], w01);
            f2 e0 = pk_fma(azp[k], z01, s0);
            e0 = pk_fma(ayp[k], y01, e0);
            e0 = pk_fma(axp[k], x01, e0);
            f2 s1 = pk_add(q2p[k + 1], w01);
            f2 e1 = pk_fma(azp[k + 1], z01, s1);
            e1 = pk_fma(ayp[k + 1], y01, e1);
            e1 = pk_fma(axp[k + 1], x01, e1);
            rmin[k]     = min3f(rmin[k],     e0[0], e0[1]);
            rmin[k + 1] = min3f(rmin[k + 1], e1[0], e1[1]);
            if (k == 0) {
                cA = min3f(e0[0], e1[0], cr[0]);     // seed with rotating acc
                cB = min3f(e0[1], e1[1], cr[1]);
            } else {
                cA = min3f(cA, e0[0], e1[0]);
                cB = min3f(cB, e0[1], e1[1]);
            }
        }
        // rotate down one lane: new[l] = old[(l+1)&63]
        cr[0] = __int_as_float(__builtin_amdgcn_ds_bpermute(rot, __float_as_int(cA)));
        cr[1] = __int_as_float(__builtin_amdgcn_ds_bpermute(rot, __float_as_int(cB)));
        idx = (idx + 1) & 63;
    }
    // after 64 iters + rotates, lane l holds pair slot l (cols ctile*128+l, +64)

    // ---- plain stores of owned partials (clamp commutes with min) ----
    #pragma unroll
    for (int k = 0; k < RPT; ++k)
        rp[((size_t)b * NCTILE + ctile) * NN + rowbase + k * TPB + tid] =
            fmaxf(rmin[k], 0.0f);
    {
        float* cbase = cp + (((size_t)b * NRTILE + rtile) * 4 + wid) * NN + ctile * CT;
        cbase[lane]      = fmaxf(cr[0], 0.0f);
        cbase[64 + lane] = fmaxf(cr[1], 0.0f);
    }
}

// 48 blocks. Blocks 0..31: rows (2048 global rows each): min over 32 ctile
// partials, then sum. Blocks 32..47: cols (one batch each): min over 8
// (rtile,wid) slices, then sum. partials[j] = block sum.
__global__ __launch_bounds__(TPB) void reduce_kernel(
        const float* __restrict__ rp, const float* __restrict__ cp,
        float* __restrict__ partials) {
    const int j = blockIdx.x;
    const int tid = threadIdx.x;
    float sum = 0.0f;
    if (j < 32) {
        #pragma unroll
        for (int r8 = 0; r8 < 8; ++r8) {
            const int gr = j * 2048 + r8 * TPB + tid;     // 0..65535
            const int b = gr >> 12, row = gr & (NN - 1);
            const float* basep = rp + (size_t)b * NCTILE * NN + row;
            float m = basep[0];
            #pragma unroll 4
            for (int c = 1; c < NCTILE; ++c) m = fminf(m, basep[(size_t)c * NN]);
            sum += m;
        }
    } else {
        const int b = j - 32;
        #pragma unroll
        for (int c16 = 0; c16 < 16; ++c16) {
            const int col = c16 * TPB + tid;
            const float* basep = cp + (size_t)b * 8 * NN + col;
            float m = basep[0];
            #pragma unroll
            for (int s = 1; s < 8; ++s) m = fminf(m, basep[(size_t)s * NN]);
            sum += m;
        }
    }
    #pragma unroll
    for (int off = 32; off > 0; off >>= 1) sum += __shfl_down(sum, off);
    __shared__ float sps[4];
    if ((tid & 63) == 0) sps[tid >> 6] = sum;
    __syncthreads();
    if (tid == 0) partials[j] = sps[0] + sps[1] + sps[2] + sps[3];
}

__global__ __launch_bounds__(TPB) void final_combine(
        const float* __restrict__ partials,
        const float* __restrict__ pred_w,  const float* __restrict__ targ_w,
        const float* __restrict__ pred_aff, const float* __restrict__ targ_aff,
        float* __restrict__ out) {
    const int tid = threadIdx.x;
    float ps = (tid < 48) ? partials[tid] : 0.0f;
    float cs = 0.0f;
    #pragma unroll
    for (int r = 0; r < (BB * KK) / TPB; ++r) {   // 2048 floats
        float d = pred_w[r * TPB + tid] - targ_w[r * TPB + tid];
        cs = fmaf(d, d, cs);
    }
    float as = 0.0f;
    if (tid < BB * 9) {
        float d = pred_aff[tid] - targ_aff[tid];
        as = d * d;
    }
    #pragma unroll
    for (int off = 32; off > 0; off >>= 1) {
        ps += __shfl_down(ps, off);
        cs += __shfl_down(cs, off);
        as += __shfl_down(as, off);
    }
    __shared__ float sps[4], scs[4], sas[4];
    const int wid = tid >> 6;
    if ((tid & 63) == 0) { sps[wid] = ps; scs[wid] = cs; sas[wid] = as; }
    __syncthreads();
    if (tid == 0) {
        float p = sps[0] + sps[1] + sps[2] + sps[3];
        float c = scs[0] + scs[1] + scs[2] + scs[3];
        float a = sas[0] + sas[1] + sas[2] + sas[3];
        float point  = p / (float)(BB * NN);   // row-min and col-min share denom
        float coeff  = c / (float)(BB * KK);
        float affine = a / (float)(BB * 9);
        out[0] = W_POINT * point + W_COEFF * coeff + W_AFFINE * affine;
        out[1] = point;
        out[2] = coeff;
        out[3] = affine;
    }
}

extern "C" void kernel_launch(void* const* d_in, const int* in_sizes, int n_in,
                              void* d_out, int out_size, void* d_ws, size_t ws_size,
                              hipStream_t stream) {
    const float* pred_shape = (const float*)d_in[0];
    const float* pred_w     = (const float*)d_in[1];
    const float* pred_aff   = (const float*)d_in[2];
    const float* targ_shape = (const float*)d_in[3];
    const float* targ_w     = (const float*)d_in[4];
    const float* targ_aff   = (const float*)d_in[5];
    float* out = (float*)d_out;

    // ws layout (all fully overwritten every call; no init needed):
    float* rp = (float*)d_ws;                              // 16*32*4096 = 8 MiB
    float* cp = rp + (size_t)BB * NCTILE * NN;             // 16*8*4096  = 2 MiB
    float* partials = cp + (size_t)BB * 8 * NN;            // 48 floats

    chamfer_kernel<<<dim3(BB * NRTILE * NCTILE), TPB, 0, stream>>>(
        pred_shape, targ_shape, targ_aff, rp, cp);
    reduce_kernel<<<48, TPB, 0, stream>>>(rp, cp, partials);
    final_combine<<<1, TPB, 0, stream>>>(partials, pred_w, targ_w,
                                         pred_aff, targ_aff, out);
}

// Round 6
// 98.996 us; speedup vs baseline: 1.4863x; 1.4863x over previous
//
#include <hip/hip_runtime.h>
#include <math.h>

#define BB 16
#define NN 4096            // N == M == 4096
#define KK 128
#define RT 2048            // rows per block  (8 per thread)
#define CT 128             // cols per block  (2 packed groups of 64)
#define RPT 8              // rows per thread
#define TPB 256
#define NRTILE (NN / RT)   // 2
#define NCTILE (NN / CT)   // 32
#define W_POINT  1.0f
#define W_COEFF  0.5f
#define W_AFFINE 0.5f

typedef float f2 __attribute__((ext_vector_type(2)));

__device__ inline float min3f(float a, float b, float c) {
    float r;
    asm("v_min3_f32 %0, %1, %2, %3" : "=v"(r) : "v"(a), "v"(b), "v"(c));
    return r;
}
__device__ inline f2 pk_add(f2 a, f2 b) {
    f2 r;
    asm("v_pk_add_f32 %0, %1, %2" : "=v"(r) : "v"(a), "v"(b));
    return r;
}
__device__ inline f2 pk_fma(f2 a, f2 b, f2 c) {
    f2 r;
    asm("v_pk_fma_f32 %0, %1, %2, %3" : "=v"(r) : "v"(a), "v"(b), "v"(c));
    return r;
}

__device__ inline void compute_affine(const float* __restrict__ aff,
                                      float R[9], float sc[3], float tr[3]) {
    float ax = aff[0], ay = aff[1], az = aff[2];
    tr[0] = aff[3]; tr[1] = aff[4]; tr[2] = aff[5];
    sc[0] = aff[6]; sc[1] = aff[7]; sc[2] = aff[8];
    float cx = cosf(ax), sx = sinf(ax);
    float cy = cosf(ay), sy = sinf(ay);
    float cz = cosf(az), sz = sinf(az);
    R[0] = cy * cz;                 R[1] = -cy * sz;                R[2] = sy;
    R[3] = cx * sz + sx * sy * cz;  R[4] = cx * cz - sx * sy * sz;  R[5] = -sx * cy;
    R[6] = sx * sz - cx * sy * cz;  R[7] = sx * cz + cx * sy * sz;  R[8] = cx * cy;
}

__device__ inline void apply_affine(const float R[9], const float sc[3], const float tr[3],
                                    float x, float y, float z,
                                    float& ox, float& oy, float& oz) {
    ox = fmaf(fmaf(x, R[0], fmaf(y, R[3], z * R[6])), sc[0], tr[0]);
    oy = fmaf(fmaf(x, R[1], fmaf(y, R[4], z * R[7])), sc[1], tr[1]);
    oz = fmaf(fmaf(x, R[2], fmaf(y, R[5], z * R[8])), sc[2], tr[2]);
}

// One-pass Chamfer, packed-fp32 inner loop. Block owns a 2048x128 tile of the
// d2 matrix (pair evaluated ONCE). Cols live in LDS as SoA float2 arrays
// pairing col s with col s+64, so both column-groups share one
// v_pk_add/v_pk_fma stream. Row-mins stay thread-local; col-mins rotate one
// lane per iter (ds_bpermute) so no cross-lane tree is needed. Cross-block
// merge via atomicMin on float-as-uint into pmin (512 KiB, L2-resident):
//   pmin[b*NN + row]            row mins
//   pmin[(BB+b)*NN + col]       col mins
__global__ __launch_bounds__(TPB, 4) void chamfer_kernel(
        const float* __restrict__ pred_shape,
        const float* __restrict__ targ_shape,
        const float* __restrict__ targ_affine,
        unsigned int* __restrict__ pmin) {
    __shared__ float ldsb[4 * CT];   // x[128] | y[128] | z[128] | w[128], pair-interleaved

    const int bx    = blockIdx.x;
    const int ctile = bx & (NCTILE - 1);
    const int rtile = (bx >> 5) & (NRTILE - 1);
    const int b     = bx >> 6;
    const int tid   = threadIdx.x;
    const int lane  = tid & 63;

    // ---- stage 128 transformed target cols (pair slot s <- cols s, s+64) ----
    if (tid < CT) {
        float R[9], sc[3], tr[3];
        compute_affine(targ_affine + b * 9, R, sc, tr);
        const int s = tid & 63, h = tid >> 6;
        const float* t = targ_shape + ((size_t)b * NN + ctile * CT + tid) * 3;
        float mx, my, mz;
        apply_affine(R, sc, tr, t[0], t[1], t[2], mx, my, mz);
        ldsb[0 * CT + 2 * s + h] = mx;
        ldsb[1 * CT + 2 * s + h] = my;
        ldsb[2 * CT + 2 * s + h] = mz;
        ldsb[3 * CT + 2 * s + h] = fmaf(mx, mx, fmaf(my, my, mz * mz));
    }

    // ---- load 8 pred rows per thread; broadcast constants as pairs ----
    const int rowbase = rtile * RT;
    f2 axp[RPT], ayp[RPT], azp[RPT], q2p[RPT];
    float rmin[RPT];
    #pragma unroll
    for (int k = 0; k < RPT; ++k) {
        const float* p = pred_shape + ((size_t)b * NN + rowbase + k * TPB + tid) * 3;
        float x = p[0], y = p[1], z = p[2];
        float q2 = fmaf(x, x, fmaf(y, y, z * z));
        axp[k] = (f2){-2.0f * x, -2.0f * x};
        ayp[k] = (f2){-2.0f * y, -2.0f * y};
        azp[k] = (f2){-2.0f * z, -2.0f * z};
        q2p[k] = (f2){q2, q2};
        rmin[k] = 1e30f;
    }
    __syncthreads();

    // ---- rotating scan: iter i, lane l handles pair slot (l+i)&63 ----
    const f2* base = (const f2*)ldsb;        // [0,64)=x [64,128)=y [128,192)=z [192,256)=w
    f2 cr = (f2){1e30f, 1e30f};              // rotating col-min accumulators (lo,hi group)
    const int rot = ((lane + 1) & 63) << 2;
    int idx = lane;
    for (int i = 0; i < 64; ++i) {
        f2 x01 = base[idx];
        f2 y01 = base[64 + idx];
        f2 z01 = base[128 + idx];
        f2 w01 = base[192 + idx];
        float cA, cB;
        #pragma unroll
        for (int k = 0; k < RPT; k += 2) {
            f2 s0 = pk_add(q2p[k], w01);
            f2 e0 = pk_fma(azp[k], z01, s0);
            e0 = pk_fma(ayp[k], y01, e0);
            e0 = pk_fma(axp[k], x01, e0);
            f2 s1 = pk_add(q2p[k + 1], w01);
            f2 e1 = pk_fma(azp[k + 1], z01, s1);
            e1 = pk_fma(ayp[k + 1], y01, e1);
            e1 = pk_fma(axp[k + 1], x01, e1);
            rmin[k]     = min3f(rmin[k],     e0[0], e0[1]);
            rmin[k + 1] = min3f(rmin[k + 1], e1[0], e1[1]);
            if (k == 0) {
                cA = min3f(e0[0], e1[0], cr[0]);     // seed with rotating acc
                cB = min3f(e0[1], e1[1], cr[1]);
            } else {
                cA = min3f(cA, e0[0], e1[0]);
                cB = min3f(cB, e0[1], e1[1]);
            }
        }
        // rotate down one lane: new[l] = old[(l+1)&63]
        cr[0] = __int_as_float(__builtin_amdgcn_ds_bpermute(rot, __float_as_int(cA)));
        cr[1] = __int_as_float(__builtin_amdgcn_ds_bpermute(rot, __float_as_int(cB)));
        idx = (idx + 1) & 63;
    }
    // after 64 iters + rotates, lane l holds pair slot l (cols ctile*128+l, +64)

    // ---- merge row-mins (clamp commutes with min; >=0 -> uint order ok) ----
    #pragma unroll
    for (int k = 0; k < RPT; ++k) {
        float d = fmaxf(rmin[k], 0.0f);
        atomicMin(&pmin[(size_t)b * NN + rowbase + k * TPB + tid],
                  __float_as_uint(d));
    }
    // ---- merge col-mins (one per lane per group, per wave) ----
    {
        float d0 = fmaxf(cr[0], 0.0f);
        atomicMin(&pmin[(size_t)(BB + b) * NN + ctile * CT + lane],
                  __float_as_uint(d0));
        float d1 = fmaxf(cr[1], 0.0f);
        atomicMin(&pmin[(size_t)(BB + b) * NN + ctile * CT + 64 + lane],
                  __float_as_uint(d1));
    }
}

// 32 blocks: block i sums pmin[i*4096 .. +4096) -> partials[i] (plain store).
__global__ __launch_bounds__(TPB) void reduce_pmin(
        const unsigned int* __restrict__ pmin,
        float* __restrict__ partials) {
    const int tid = threadIdx.x;
    const uint4* pm4 = (const uint4*)(pmin + (size_t)blockIdx.x * 4096);
    float ps = 0.0f;
    #pragma unroll
    for (int r = 0; r < 4; ++r) {                 // 1024 uint4 per block
        uint4 u = pm4[r * TPB + tid];
        ps += __uint_as_float(u.x) + __uint_as_float(u.y)
            + __uint_as_float(u.z) + __uint_as_float(u.w);
    }
    #pragma unroll
    for (int off = 32; off > 0; off >>= 1) ps += __shfl_down(ps, off);
    __shared__ float sps[4];
    if ((tid & 63) == 0) sps[tid >> 6] = ps;
    __syncthreads();
    if (tid == 0) partials[blockIdx.x] = sps[0] + sps[1] + sps[2] + sps[3];
}

__global__ __launch_bounds__(TPB) void final_combine(
        const float* __restrict__ partials,
        const float* __restrict__ pred_w,  const float* __restrict__ targ_w,
        const float* __restrict__ pred_aff, const float* __restrict__ targ_aff,
        float* __restrict__ out) {
    const int tid = threadIdx.x;
    float ps = (tid < 32) ? partials[tid] : 0.0f;
    float cs = 0.0f;
    #pragma unroll
    for (int r = 0; r < (BB * KK) / TPB; ++r) {   // 2048 floats
        float d = pred_w[r * TPB + tid] - targ_w[r * TPB + tid];
        cs = fmaf(d, d, cs);
    }
    float as = 0.0f;
    if (tid < BB * 9) {
        float d = pred_aff[tid] - targ_aff[tid];
        as = d * d;
    }
    #pragma unroll
    for (int off = 32; off > 0; off >>= 1) {
        ps += __shfl_down(ps, off);
        cs += __shfl_down(cs, off);
        as += __shfl_down(as, off);
    }
    __shared__ float sps[4], scs[4], sas[4];
    const int wid = tid >> 6;
    if ((tid & 63) == 0) { sps[wid] = ps; scs[wid] = cs; sas[wid] = as; }
    __syncthreads();
    if (tid == 0) {
        float p = sps[0] + sps[1] + sps[2] + sps[3];
        float c = scs[0] + scs[1] + scs[2] + scs[3];
        float a = sas[0] + sas[1] + sas[2] + sas[3];
        float point  = p / (float)(BB * NN);   // row-min and col-min share denom
        float coeff  = c / (float)(BB * KK);
        float affine = a / (float)(BB * 9);
        out[0] = W_POINT * point + W_COEFF * coeff + W_AFFINE * affine;
        out[1] = point;
        out[2] = coeff;
        out[3] = affine;
    }
}

extern "C" void kernel_launch(void* const* d_in, const int* in_sizes, int n_in,
                              void* d_out, int out_size, void* d_ws, size_t ws_size,
                              hipStream_t stream) {
    const float* pred_shape = (const float*)d_in[0];
    const float* pred_w     = (const float*)d_in[1];
    const float* pred_aff   = (const float*)d_in[2];
    const float* targ_shape = (const float*)d_in[3];
    const float* targ_w     = (const float*)d_in[4];
    const float* targ_aff   = (const float*)d_in[5];
    float* out = (float*)d_out;
    unsigned int* pmin = (unsigned int*)d_ws;            // rows [0,64K) + cols [64K,128K)
    float* partials = (float*)(pmin + 2 * BB * NN);      // 32 floats

    // init mins to a huge positive float (0x7f7f7f7f = 3.39e38)
    hipMemsetAsync(pmin, 0x7f, (size_t)2 * BB * NN * sizeof(unsigned int), stream);

    chamfer_kernel<<<dim3(BB * NRTILE * NCTILE), TPB, 0, stream>>>(
        pred_shape, targ_shape, targ_aff, pmin);
    reduce_pmin<<<32, TPB, 0, stream>>>(pmin, partials);
    final_combine<<<1, TPB, 0, stream>>>(partials, pred_w, targ_w,
                                         pred_aff, targ_aff, out);
}